// Round 14
// baseline (274.844 us; speedup 1.0000x reference)
//
#include <hip/hip_runtime.h>
#include <hip/hip_cooperative_groups.h>
#include <math.h>
#include <stdint.h>

namespace cg = cooperative_groups;

#define NTOK 8192
#define DIM  512
#define NEXP 8
#define HIDN 512
#define BM 64                 // row tile (tokens)
#define BN 128                // col tile
#define BK 32
#define NT  (DIM / BK)        // 16 K-steps
#define MAXRB 136             // ceil((8192 + 8*63)/64)
#define SLOTS (MAXRB*BM)      // 8704
#define GBLK (NTOK/16)        // 512 gate blocks (16 tokens each)
#define FBLK 512              // cooperative front grid

typedef _Float16 f16;
typedef __attribute__((ext_vector_type(4))) _Float16 f16x4;
typedef __attribute__((ext_vector_type(8))) _Float16 f16x8;
typedef __attribute__((ext_vector_type(4))) float    f32x4;

__device__ __forceinline__ void gl2lds16(const void* g, void* l) {
  __builtin_amdgcn_global_load_lds(
      (const __attribute__((address_space(1))) unsigned int*)(g),
      (__attribute__((address_space(3))) unsigned int*)(l), 16, 0, 0);
}

struct FrontArgs {
  const float* x;  f16* xh;
  const float* W1; const float* W2; f16* W1t; f16* W2t;
  const float* Wo; const float* gW; double* G1;
  const float* Wv; const float* bv; const float* bo; const float* gb;
  float* Wg; double* bg;
  const float* q;  float* gp_out;
  int* e1a; int* e2a; float* w1a; float* w2a; int* r1a; int* r2a;
  int* hist; float* gpsum;
  int* aoff; int* counts; int* toks; float* wsl; float* loss;
};

union SMem {
  struct { float qs[16 * 513]; float ps[16][8]; int cnt[16]; } g;      // gate
  struct { float t[32][33]; } tr;                                      // transpose
  struct {
    int sfull[16][16]; int sbelow[16][16];
    int tot[16]; int pre[16]; int s_ao[16];
    double simp[32][8]; double imp[8];
  } r;                                                                 // route
};

// ---------- cooperative front: prep | foldB | gate | route ----------
__global__ __launch_bounds__(256) void k_front(FrontArgs a) {
  cg::grid_group grid = cg::this_grid();
  __shared__ SMem sm;
  const int tid = threadIdx.x;
  const int b = blockIdx.x;

  // ===== P0: x-convert (0..4095) | W transpose (4096..8191) | foldA (8192..9215)
  for (int u = b; u < 9216; u += FBLK) {
    if (u < 4096) {
      int i4 = (u * 256 + tid) * 4;
      float4 v = *(const float4*)(a.x + i4);
      f16x4 o; o.x = (_Float16)v.x; o.y = (_Float16)v.y; o.z = (_Float16)v.z; o.w = (_Float16)v.w;
      *(f16x4*)(a.xh + i4) = o;
    } else if (u < 8192) {
      int idx = u - 4096;
      int z = idx >> 8, rem = idx & 255;
      int k0 = (rem >> 4) * 32, n0 = (rem & 15) * 32;
      const float* src = (z < 8 ? a.W1 : a.W2) + (size_t)(z & 7) * DIM * DIM;
      f16* dst = (z < 8 ? a.W1t : a.W2t) + (size_t)(z & 7) * DIM * DIM;
      int tx = tid & 31, ty = tid >> 5;
      __syncthreads();
      for (int r = ty; r < 32; r += 8) sm.tr.t[r][tx] = src[(size_t)(k0 + r) * DIM + n0 + tx];
      __syncthreads();
      for (int r = ty; r < 32; r += 8) dst[(size_t)(n0 + r) * DIM + k0 + tx] = (f16)sm.tr.t[tx][r];
      __syncthreads();
    } else {
      int out = (u - 8192) * 4 + (tid >> 6);
      int lane = tid & 63;
      int d = out >> 3, e = out & 7;
      double acc = 0.0;
#pragma unroll
      for (int j = 0; j < 8; j++) {
        int k = j * 64 + lane;
        acc += (double)a.Wo[d * DIM + k] * (double)a.gW[k * NEXP + e];
      }
#pragma unroll
      for (int off = 32; off; off >>= 1) acc += __shfl_xor(acc, off, 64);
      if (lane == 0) a.G1[out] = acc;
    }
  }
  grid.sync();

  // ===== P1: foldB (units 0..1023: Wg; unit 1024: bg)
  for (int u = b; u < 1025; u += FBLK) {
    int lane = tid & 63;
    if (u == 1024) {
      int w = tid >> 6;
      for (int e = w; e < NEXP; e += 4) {
        double acc = 0.0;
#pragma unroll
        for (int j = 0; j < 8; j++) {
          int d = j * 64 + lane;
          acc += (double)a.bv[d] * a.G1[d * NEXP + e] + (double)a.bo[d] * (double)a.gW[d * NEXP + e];
        }
#pragma unroll
        for (int off = 32; off; off >>= 1) acc += __shfl_xor(acc, off, 64);
        if (lane == 0) a.bg[e] = acc + (double)a.gb[e];
      }
    } else {
      int out = u * 4 + (tid >> 6);
      int d = out >> 3, e = out & 7;
      double acc = 0.0;
#pragma unroll
      for (int j = 0; j < 8; j++) {
        int k = j * 64 + lane;
        acc += (double)a.Wv[d * DIM + k] * a.G1[k * NEXP + e];
      }
#pragma unroll
      for (int off = 32; off; off >>= 1) acc += __shfl_xor(acc, off, 64);
      if (lane == 0) a.Wg[out] = (float)acc;
    }
  }
  grid.sync();

  // ===== P2: gate (block b handles tokens b*16..b*16+15)
  {
    const int tok0 = b * 16;
    __syncthreads();
    for (int i = tid; i < 16 * 512; i += 256) {
      int r = i >> 9, c = i & 511;
      sm.g.qs[r * 513 + c] = a.q[(size_t)(tok0 + r) * DIM + c];
    }
    if (tid < 16) sm.g.cnt[tid] = 0;
    __syncthreads();

    const int e = tid & 7;
    const int half = (tid >> 3) & 1;
    const int tl = tid >> 4;
    const float* qrow = sm.g.qs + tl * 513 + half * 256;
    const float* wcol = a.Wg + half * 256 * NEXP + e;

    double a0 = 0, a1 = 0, a2 = 0, a3 = 0;
#pragma unroll 4
    for (int j = 0; j < 256; j += 4) {
      a0 += (double)qrow[j]     * (double)wcol[(size_t)j * NEXP];
      a1 += (double)qrow[j + 1] * (double)wcol[(size_t)(j + 1) * NEXP];
      a2 += (double)qrow[j + 2] * (double)wcol[(size_t)(j + 2) * NEXP];
      a3 += (double)qrow[j + 3] * (double)wcol[(size_t)(j + 3) * NEXP];
    }
    double acc = (a0 + a1) + (a2 + a3);
    acc += __shfl_xor(acc, 8, 64);  // combine halves

    double l = acc + a.bg[e];
    double m = l;
#pragma unroll
    for (int off = 1; off < 8; off <<= 1) m = fmax(m, __shfl_xor(m, off, 64));
    float ex = expf((float)(l - m));
    float s = ex;
#pragma unroll
    for (int off = 1; off < 8; off <<= 1) s += __shfl_xor(s, off, 64);
    float pf = ex / s;
    int tok = tok0 + tl;
    if (half == 0) { a.gp_out[(size_t)tok * NEXP + e] = pf; sm.g.ps[tl][e] = pf; }

    double v1 = l; int i1 = e;
#pragma unroll
    for (int off = 1; off < 8; off <<= 1) {
      double ov = __shfl_xor(v1, off, 64);
      int oi = __shfl_xor(i1, off, 64);
      if (ov > v1 || (ov == v1 && oi < i1)) { v1 = ov; i1 = oi; }
    }
    double v2 = (e == i1) ? -1e300 : l; int i2 = e;
#pragma unroll
    for (int off = 1; off < 8; off <<= 1) {
      double ov = __shfl_xor(v2, off, 64);
      int oi = __shfl_xor(i2, off, 64);
      if (ov > v2 || (ov == v2 && oi < i2)) { v2 = ov; i2 = oi; }
    }
    float p1 = __shfl(pf, (tl << 4) + i1, 64);
    float p2 = __shfl(pf, (tl << 4) + i2, 64);
    if (e == 0 && half == 0) {
      float ev = expf(p2 - p1);
      float iw = 1.0f / (1.0f + ev);
      a.e1a[tok] = i1; a.e2a[tok] = i2;
      a.w1a[tok] = iw; a.w2a[tok] = ev * iw;
      a.r1a[tok] = atomicAdd(&sm.g.cnt[i1], 1);
      a.r2a[tok] = atomicAdd(&sm.g.cnt[8 + i2], 1);
    }
    __syncthreads();
    if (tid < 16) a.hist[b * 16 + tid] = sm.g.cnt[tid];
    if (tid < 8) {
      float ssum = 0.f;
#pragma unroll
      for (int r = 0; r < 16; r++) ssum += sm.g.ps[r][tid];
      a.gpsum[b * 8 + tid] = ssum;
    }
  }
  grid.sync();

  // ===== P3: route (block b scatters its 16 tokens; block 0 writes globals)
  {
    const int c = tid & 15, seg = tid >> 4;   // 16 segs x 32 gate-blocks
    int fullsum = 0, belowsum = 0;
    for (int j = 0; j < 32; j++) {
      int blk = seg * 32 + j;
      int h = a.hist[blk * 16 + c];
      fullsum += h;
      if (blk < b) belowsum += h;
    }
    __syncthreads();
    sm.r.sfull[seg][c] = fullsum; sm.r.sbelow[seg][c] = belowsum;
    __syncthreads();
    if (tid < 16) {
      int f = 0, bl = 0;
#pragma unroll
      for (int s2 = 0; s2 < 16; s2++) { f += sm.r.sfull[s2][tid]; bl += sm.r.sbelow[s2][tid]; }
      sm.r.tot[tid] = f; sm.r.pre[tid] = bl;
    }
    __syncthreads();
    if (tid == 0) {
      int o0 = 0, o1 = 0;
#pragma unroll
      for (int e = 0; e < NEXP; e++) {
        sm.r.s_ao[e] = o0;     o0 += (sm.r.tot[e] + BM - 1) / BM * BM;
        sm.r.s_ao[8 + e] = o1; o1 += (sm.r.tot[8 + e] + BM - 1) / BM * BM;
      }
      if (b == 0) {
        int p0 = 0, p1 = 0;
#pragma unroll
        for (int e = 0; e < NEXP; e++) {
          a.counts[e] = sm.r.tot[e];         a.aoff[e] = p0;     p0 += (sm.r.tot[e] + BM - 1) / BM * BM;
          a.counts[8 + e] = sm.r.tot[8 + e]; a.aoff[9 + e] = p1; p1 += (sm.r.tot[8 + e] + BM - 1) / BM * BM;
        }
        a.aoff[8] = p0; a.aoff[17] = p1;
      }
    }
    __syncthreads();
    if (b == 0) {
      // pad-fill: counter cc handled by 16 threads
      const int cc = tid >> 4, ll = tid & 15;
      const int cnt_c = sm.r.tot[cc];
      const int padded = (cnt_c + BM - 1) / BM * BM;
      const int base = ((cc >> 3) ? SLOTS : 0) + sm.r.s_ao[cc];
      for (int sidx = cnt_c + ll; sidx < padded; sidx += 16)
        a.toks[base + sidx] = 0;
      // importance loss
      {
        const int e = tid & 7, j0 = tid >> 3;   // 32 groups x 8 experts
        double acc2 = 0.0;
        for (int k = 0; k < 16; k++)
          acc2 += (double)a.gpsum[(size_t)(j0 + 32 * k) * 8 + e];
        sm.r.simp[j0][e] = acc2;
      }
      __syncthreads();
      if (tid < 8) {
        double s2 = 0.0;
        for (int j = 0; j < 32; j++) s2 += sm.r.simp[j][tid];
        sm.r.imp[tid] = s2;
      }
      __syncthreads();
      if (tid == 0) {
        double mn = 0.0;
        for (int e = 0; e < 8; e++) mn += sm.r.imp[e];
        mn *= (1.0 / 8.0);
        double var = 0.0;
        for (int e = 0; e < 8; e++) { double d = sm.r.imp[e] - mn; var += d * d; }
        var *= (1.0 / 7.0);
        double r = sqrt(var) / mn;
        a.loss[0] = (float)(0.01 * r * r);
      }
    }
    // scatter this block's 16 tokens
    if (tid < 16) {
      int n = b * 16 + tid;
      int E1 = a.e1a[n];
      int slot = sm.r.s_ao[E1] + sm.r.pre[E1] + a.r1a[n];
      a.toks[slot] = n; a.wsl[slot] = a.w1a[n];
      int E2 = a.e2a[n];
      slot = SLOTS + sm.r.s_ao[8 + E2] + sm.r.pre[8 + E2] + a.r2a[n];
      a.toks[slot] = n; a.wsl[slot] = a.w2a[n];
    }
  }
}

// ---------- expert GEMM: 64x128 tile, safe 2-phase dbuf (R13-proven) ----------
// MODE 0: layer1 (x->H, relu), z = klist.
// MODE 1: layer2, z = klist; k0 -> y (=), k1 -> ypart (=).
template <int MODE>
__global__ __launch_bounds__(256) void k_expert(
    const f16* __restrict__ Asrc, const f16* __restrict__ Wt,
    const float* __restrict__ bias, const int* __restrict__ toks,
    const float* __restrict__ wsl, const int* __restrict__ aoff,
    const int* __restrict__ counts, f16* __restrict__ Hout,
    float* __restrict__ y, float* __restrict__ ypart) {
  const int klist = blockIdx.z;
  const int* ao = aoff + klist * 9;
  const int slot0 = blockIdx.x * BM;
  if (slot0 >= ao[8]) return;
  int e = 0;
#pragma unroll
  for (int t = 1; t <= 7; t++) if (slot0 >= ao[t]) e = t;

  const int n0 = blockIdx.y * BN;
  const int tid = threadIdx.x, lane = tid & 63, wid = tid >> 6;

  __shared__ __align__(16) f16 As[2][BM * BK];   // 64x32
  __shared__ __align__(16) f16 Bs[2][BN * BK];   // 128x32

  const int srow = wid * 16 + (lane >> 2);       // 0..63
  const int scol = (lane & 3) * 8;

  const f16* arow;
  if (MODE == 0) {
    int tk = toks[klist * SLOTS + slot0 + srow];
    arow = Asrc + (size_t)tk * DIM + scol;
  } else {
    arow = Asrc + (size_t)(klist * SLOTS + slot0 + srow) * HIDN + scol;
  }
  const f16* brow[2];
  int bloff[2];
#pragma unroll
  for (int rnd = 0; rnd < 2; rnd++) {
    brow[rnd] = Wt + ((size_t)e * DIM + n0 + rnd * 64 + srow) * DIM + scol;
    bloff[rnd] = (rnd * 64 + wid * 16) * BK;
  }
  const int aloff = wid * 16 * BK;

  f32x4 acc[4][2] = {};
  const int fr = lane & 15, kb = (lane >> 4) * 8;

#define STAGE(buf, ks)                                    \
  {                                                       \
    gl2lds16(arow + (ks), As[buf] + aloff);               \
    _Pragma("unroll")                                     \
    for (int rnd = 0; rnd < 2; rnd++)                     \
      gl2lds16(brow[rnd] + (ks), Bs[buf] + bloff[rnd]);   \
  }

  STAGE(0, 0);
  __syncthreads();
  for (int t = 0; t < NT; t++) {
    const int cur = t & 1;
    if (t + 1 < NT) STAGE(cur ^ 1, (t + 1) * BK);   // overlap with compute below
    f16x8 af[4], bf[2];
#pragma unroll
    for (int m = 0; m < 4; m++)
      af[m] = *(const f16x8*)(As[cur] + (m * 16 + fr) * BK + kb);
#pragma unroll
    for (int n = 0; n < 2; n++)
      bf[n] = *(const f16x8*)(Bs[cur] + (wid * 32 + n * 16 + fr) * BK + kb);
#pragma unroll
    for (int m = 0; m < 4; m++)
#pragma unroll
      for (int n = 0; n < 2; n++)
        acc[m][n] = __builtin_amdgcn_mfma_f32_16x16x32_f16(af[m], bf[n], acc[m][n], 0, 0, 0);
    __syncthreads();   // drains next-tile loads + retires this tile's LDS reads
  }
#undef STAGE

  float bcol[2];
#pragma unroll
  for (int n = 0; n < 2; n++)
    bcol[n] = bias[e * ((MODE == 0) ? HIDN : DIM) + n0 + wid * 32 + n * 16 + fr];

  if (MODE == 0) {
#pragma unroll
    for (int m = 0; m < 4; m++)
#pragma unroll
      for (int r4 = 0; r4 < 4; r4++) {
        int slot = slot0 + m * 16 + (lane >> 4) * 4 + r4;
#pragma unroll
        for (int n = 0; n < 2; n++) {
          int col = n0 + wid * 32 + n * 16 + fr;
          float v = acc[m][n][r4] + bcol[n];
          Hout[(size_t)(klist * SLOTS + slot) * HIDN + col] = (f16)fmaxf(v, 0.f);
        }
      }
  } else {
    float* yo = (klist == 0) ? y : ypart;
    const int vend = ao[e] + counts[klist * 8 + e];
#pragma unroll
    for (int m = 0; m < 4; m++)
#pragma unroll
      for (int r4 = 0; r4 < 4; r4++) {
        int slot = slot0 + m * 16 + (lane >> 4) * 4 + r4;
        if (slot < vend) {
          int tk = toks[klist * SLOTS + slot];
          float w = wsl[klist * SLOTS + slot];
#pragma unroll
          for (int n = 0; n < 2; n++) {
            int col = n0 + wid * 32 + n * 16 + fr;
            yo[(size_t)tk * DIM + col] = (acc[m][n][r4] + bcol[n]) * w;
          }
        }
      }
  }
}

// ---------- combine: y += ypart ----------
__global__ __launch_bounds__(256) void k_combine(float* __restrict__ y,
                                                 const float* __restrict__ ypart) {
  size_t i4 = ((size_t)blockIdx.x * 256 + threadIdx.x) * 4;
  float4 a = *(const float4*)(y + i4);
  float4 b = *(const float4*)(ypart + i4);
  a.x += b.x; a.y += b.y; a.z += b.z; a.w += b.w;
  *(float4*)(y + i4) = a;
}

extern "C" void kernel_launch(void* const* d_in, const int* in_sizes, int n_in,
                              void* d_out, int out_size, void* d_ws, size_t ws_size,
                              hipStream_t stream) {
  const float* x  = (const float*)d_in[0];
  const float* q  = (const float*)d_in[1];
  const float* Wv = (const float*)d_in[6];
  const float* bv = (const float*)d_in[7];
  const float* Wo = (const float*)d_in[8];
  const float* bo = (const float*)d_in[9];
  const float* gW = (const float*)d_in[10];
  const float* gb = (const float*)d_in[11];
  const float* W1 = (const float*)d_in[12];
  const float* b1 = (const float*)d_in[13];
  const float* W2 = (const float*)d_in[14];
  const float* b2 = (const float*)d_in[15];

  float* out = (float*)d_out;
  float* y_out = out;
  float* gp_out = out + (size_t)NTOK * DIM;
  float* loss_out = gp_out + (size_t)NTOK * NEXP;

  uint8_t* w = (uint8_t*)d_ws;
  size_t o = 0;
  auto alloc = [&](size_t bytes) -> void* {
    void* p = w + o;
    o = (o + bytes + 255) & ~(size_t)255;
    return p;
  };
  f16* xh      = (f16*)alloc((size_t)NTOK * DIM * 2);
  f16* W1t     = (f16*)alloc((size_t)NEXP * DIM * HIDN * 2);
  f16* W2t     = (f16*)alloc((size_t)NEXP * DIM * HIDN * 2);
  f16* Hbuf    = (f16*)alloc((size_t)2 * SLOTS * HIDN * 2);
  float* ypart = (float*)alloc((size_t)NTOK * DIM * 4);
  double* G1   = (double*)alloc((size_t)DIM * NEXP * 8);
  float* Wg    = (float*)alloc((size_t)DIM * NEXP * 4);
  double* bg   = (double*)alloc(NEXP * 8);
  int* e1a     = (int*)alloc(NTOK * 4);
  int* e2a     = (int*)alloc(NTOK * 4);
  float* w1a   = (float*)alloc(NTOK * 4);
  float* w2a   = (float*)alloc(NTOK * 4);
  int* r1a     = (int*)alloc(NTOK * 4);
  int* r2a     = (int*)alloc(NTOK * 4);
  int* hist    = (int*)alloc((size_t)GBLK * 16 * 4);
  float* gpsum = (float*)alloc((size_t)GBLK * 8 * 4);
  int* counts  = (int*)alloc(16 * 4);
  int* aoff    = (int*)alloc(18 * 4);
  int* toks    = (int*)alloc((size_t)2 * SLOTS * 4);
  float* wsl   = (float*)alloc((size_t)2 * SLOTS * 4);
  (void)ws_size; (void)in_sizes; (void)n_in; (void)out_size;

  FrontArgs fa;
  fa.x = x; fa.xh = xh;
  fa.W1 = W1; fa.W2 = W2; fa.W1t = W1t; fa.W2t = W2t;
  fa.Wo = Wo; fa.gW = gW; fa.G1 = G1;
  fa.Wv = Wv; fa.bv = bv; fa.bo = bo; fa.gb = gb;
  fa.Wg = Wg; fa.bg = bg;
  fa.q = q; fa.gp_out = gp_out;
  fa.e1a = e1a; fa.e2a = e2a; fa.w1a = w1a; fa.w2a = w2a; fa.r1a = r1a; fa.r2a = r2a;
  fa.hist = hist; fa.gpsum = gpsum;
  fa.aoff = aoff; fa.counts = counts; fa.toks = toks; fa.wsl = wsl; fa.loss = loss_out;

  void* kargs[] = { &fa };
  hipLaunchCooperativeKernel((const void*)k_front, dim3(FBLK), dim3(256), kargs, 0, stream);

  k_expert<0><<<dim3(MAXRB, 4, 2), 256, 0, stream>>>(xh, W1t, b1, toks, wsl, aoff, counts,
                                                     Hbuf, nullptr, nullptr);
  k_expert<1><<<dim3(MAXRB, 4, 2), 256, 0, stream>>>(Hbuf, W2t, b2, toks, wsl, aoff, counts,
                                                     nullptr, y_out, ypart);
  k_combine<<<NTOK * DIM / 1024, 256, 0, stream>>>(y_out, ypart);
}

// Round 15
// 101.627 us; speedup vs baseline: 2.7044x; 2.7044x over previous
//
#include <hip/hip_runtime.h>
#include <math.h>
#include <stdint.h>

#define NTOK 8192
#define DIM  512
#define NEXP 8
#define HIDN 512
#define BM 64                 // row tile (tokens)
#define BN 128                // col tile
#define BK 32
#define NT  (DIM / BK)        // 16 K-steps
#define MAXRB 136             // ceil((8192 + 8*63)/64)
#define SLOTS (MAXRB*BM)      // 8704
#define GBLK (NTOK/16)        // 512 gate blocks (16 tokens each)

typedef _Float16 f16;
typedef __attribute__((ext_vector_type(4))) _Float16 f16x4;
typedef __attribute__((ext_vector_type(8))) _Float16 f16x8;
typedef __attribute__((ext_vector_type(4))) float    f32x4;

__device__ __forceinline__ void gl2lds16(const void* g, void* l) {
  __builtin_amdgcn_global_load_lds(
      (const __attribute__((address_space(1))) unsigned int*)(g),
      (__attribute__((address_space(3))) unsigned int*)(l), 16, 0, 0);
}

// ---------- prep: x->f16 | W1/W2 transpose-cast | foldA (G1 = Wo @ gate_W) ----------
__global__ __launch_bounds__(256) void k_prep(
    const float* __restrict__ x, f16* __restrict__ xh,
    const float* __restrict__ W1, const float* __restrict__ W2,
    f16* __restrict__ W1t, f16* __restrict__ W2t,
    const float* __restrict__ Wo, const float* __restrict__ gW,
    double* __restrict__ G1) {
  const int bx = blockIdx.x, tid = threadIdx.x;
  if (bx < 4096) {               // x convert
    int i4 = (bx * 256 + tid) * 4;
    float4 v = *(const float4*)(x + i4);
    f16x4 o; o.x = (_Float16)v.x; o.y = (_Float16)v.y; o.z = (_Float16)v.z; o.w = (_Float16)v.w;
    *(f16x4*)(xh + i4) = o;
  } else if (bx < 8192) {        // weight transpose-cast
    __shared__ float t[32][33];
    int idx = bx - 4096;
    int z = idx >> 8, rem = idx & 255;
    int k0 = (rem >> 4) * 32, n0 = (rem & 15) * 32;
    const float* src = (z < 8 ? W1 : W2) + (size_t)(z & 7) * DIM * DIM;
    f16* dst = (z < 8 ? W1t : W2t) + (size_t)(z & 7) * DIM * DIM;
    int tx = tid & 31, ty = tid >> 5;
    for (int r = ty; r < 32; r += 8) t[r][tx] = src[(size_t)(k0 + r) * DIM + n0 + tx];
    __syncthreads();
    for (int r = ty; r < 32; r += 8) dst[(size_t)(n0 + r) * DIM + k0 + tx] = (f16)t[tx][r];
  } else {                       // foldA: G1[d][e] = sum_k Wo[d][k] * gW[k][e]  (fp64)
    int out = (bx - 8192) * 4 + (tid >> 6);
    int lane = tid & 63;
    int d = out >> 3, e = out & 7;
    double acc = 0.0;
#pragma unroll
    for (int j = 0; j < 8; j++) {
      int k = j * 64 + lane;
      acc += (double)Wo[d * DIM + k] * (double)gW[k * NEXP + e];
    }
#pragma unroll
    for (int off = 32; off; off >>= 1) acc += __shfl_xor(acc, off, 64);
    if (lane == 0) G1[out] = acc;
  }
}

// blocks 0..1023: Wg = fp32(Wv @ G1). block 1024: bg fold.
__global__ void k_foldB(const float* __restrict__ Wv, const double* __restrict__ G1,
                        float* __restrict__ Wg, const float* __restrict__ bv,
                        const float* __restrict__ bo, const float* __restrict__ gW,
                        const float* __restrict__ gb, double* __restrict__ bg) {
  int lane = threadIdx.x & 63;
  if (blockIdx.x == 1024) {
    int w = threadIdx.x >> 6;
    for (int e = w; e < NEXP; e += 4) {
      double acc = 0.0;
#pragma unroll
      for (int j = 0; j < 8; j++) {
        int d = j * 64 + lane;
        acc += (double)bv[d] * G1[d * NEXP + e] + (double)bo[d] * (double)gW[d * NEXP + e];
      }
#pragma unroll
      for (int off = 32; off; off >>= 1) acc += __shfl_xor(acc, off, 64);
      if (lane == 0) bg[e] = acc + (double)gb[e];
    }
    return;
  }
  int out = blockIdx.x * 4 + (threadIdx.x >> 6);
  int d = out >> 3, e = out & 7;
  double acc = 0.0;
#pragma unroll
  for (int j = 0; j < 8; j++) {
    int k = j * 64 + lane;
    acc += (double)Wv[d * DIM + k] * G1[k * NEXP + e];
  }
#pragma unroll
  for (int off = 32; off; off >>= 1) acc += __shfl_xor(acc, off, 64);
  if (lane == 0) Wg[out] = (float)acc;
}

// ---------- gate: thread-per-(token,expert,half). fp64 logits, fp32 softmax. ----------
__global__ __launch_bounds__(256) void k_gate(
    const float* __restrict__ q, const float* __restrict__ Wg,
    const double* __restrict__ bg, float* __restrict__ gp_out,
    int* __restrict__ e1a, int* __restrict__ e2a,
    float* __restrict__ w1a, float* __restrict__ w2a,
    int* __restrict__ r1a, int* __restrict__ r2a, int* __restrict__ hist,
    float* __restrict__ gpsum) {
  __shared__ float qs[16 * 513];
  __shared__ float ps[16][8];
  __shared__ int cnt[16];
  const int tid = threadIdx.x;
  const int tok0 = blockIdx.x * 16;

  for (int i = tid; i < 16 * 512; i += 256) {
    int r = i >> 9, c = i & 511;
    qs[r * 513 + c] = q[(size_t)(tok0 + r) * DIM + c];
  }
  if (tid < 16) cnt[tid] = 0;
  __syncthreads();

  const int e = tid & 7;
  const int half = (tid >> 3) & 1;
  const int tl = tid >> 4;
  const float* qrow = qs + tl * 513 + half * 256;
  const float* wcol = Wg + half * 256 * NEXP + e;

  double a0 = 0, a1 = 0, a2 = 0, a3 = 0;
#pragma unroll 4
  for (int j = 0; j < 256; j += 4) {
    a0 += (double)qrow[j]     * (double)wcol[(size_t)j * NEXP];
    a1 += (double)qrow[j + 1] * (double)wcol[(size_t)(j + 1) * NEXP];
    a2 += (double)qrow[j + 2] * (double)wcol[(size_t)(j + 2) * NEXP];
    a3 += (double)qrow[j + 3] * (double)wcol[(size_t)(j + 3) * NEXP];
  }
  double acc = (a0 + a1) + (a2 + a3);
  acc += __shfl_xor(acc, 8, 64);  // combine halves

  double l = acc + bg[e];
  double m = l;
#pragma unroll
  for (int off = 1; off < 8; off <<= 1) m = fmax(m, __shfl_xor(m, off, 64));
  float ex = expf((float)(l - m));
  float s = ex;
#pragma unroll
  for (int off = 1; off < 8; off <<= 1) s += __shfl_xor(s, off, 64);
  float pf = ex / s;
  int tok = tok0 + tl;
  if (half == 0) { gp_out[(size_t)tok * NEXP + e] = pf; ps[tl][e] = pf; }

  // top-1/top-2 ordered by fp64 logit (monotone == prob ordering)
  double v1 = l; int i1 = e;
#pragma unroll
  for (int off = 1; off < 8; off <<= 1) {
    double ov = __shfl_xor(v1, off, 64);
    int oi = __shfl_xor(i1, off, 64);
    if (ov > v1 || (ov == v1 && oi < i1)) { v1 = ov; i1 = oi; }
  }
  double v2 = (e == i1) ? -1e300 : l; int i2 = e;
#pragma unroll
  for (int off = 1; off < 8; off <<= 1) {
    double ov = __shfl_xor(v2, off, 64);
    int oi = __shfl_xor(i2, off, 64);
    if (ov > v2 || (ov == v2 && oi < i2)) { v2 = ov; i2 = oi; }
  }
  float p1 = __shfl(pf, (tl << 4) + i1, 64);
  float p2 = __shfl(pf, (tl << 4) + i2, 64);
  if (e == 0 && half == 0) {
    float ev = expf(p2 - p1);
    float iw = 1.0f / (1.0f + ev);
    e1a[tok] = i1; e2a[tok] = i2;
    w1a[tok] = iw; w2a[tok] = ev * iw;
    r1a[tok] = atomicAdd(&cnt[i1], 1);
    r2a[tok] = atomicAdd(&cnt[8 + i2], 1);
  }
  __syncthreads();
  if (tid < 16) hist[blockIdx.x * 16 + tid] = cnt[tid];
  if (tid < 8) {
    float ssum = 0.f;
#pragma unroll
    for (int r = 0; r < 16; r++) ssum += ps[r][tid];
    gpsum[blockIdx.x * 8 + tid] = ssum;
  }
}

// ---------- route: fused scan + scatter (+ pads, counts/aoff, imploss) ----------
__global__ __launch_bounds__(1024) void k_route(
    const int* __restrict__ hist,
    const int* __restrict__ e1a, const int* __restrict__ e2a,
    const float* __restrict__ w1a, const float* __restrict__ w2a,
    const int* __restrict__ r1a, const int* __restrict__ r2a,
    int* __restrict__ aoff, int* __restrict__ counts,
    int* __restrict__ toks, float* __restrict__ wsl,
    const float* __restrict__ gpsum, float* __restrict__ loss) {
  __shared__ int bb[GBLK][16];   // exclusive prefix per (gate-block, counter)
  __shared__ int tot[16];
  __shared__ int s_ao[16];
  __shared__ double imp[8];
  const int c = threadIdx.x >> 6;   // counter 0..15
  const int l = threadIdx.x & 63;
  int v[GBLK / 64];
  int s = 0;
#pragma unroll
  for (int j = 0; j < GBLK / 64; j++) {
    v[j] = hist[((l * (GBLK / 64) + j) << 4) + c];
    s += v[j];
  }
  int incl = s;
#pragma unroll
  for (int off = 1; off < 64; off <<= 1) {
    int t = __shfl_up(incl, off, 64);
    if (l >= off) incl += t;
  }
  int run = incl - s;  // exclusive
#pragma unroll
  for (int j = 0; j < GBLK / 64; j++) {
    bb[l * (GBLK / 64) + j][c] = run;
    run += v[j];
  }
  if (l == 63) tot[c] = incl;
  __syncthreads();
  if (threadIdx.x == 0) {
    int o0 = 0, o1 = 0;
#pragma unroll
    for (int e = 0; e < NEXP; e++) {
      s_ao[e] = o0;     o0 += (tot[e] + BM - 1) / BM * BM;
      s_ao[8 + e] = o1; o1 += (tot[8 + e] + BM - 1) / BM * BM;
    }
    if (blockIdx.x == 0) {
      int p0 = 0, p1 = 0;
#pragma unroll
      for (int e = 0; e < NEXP; e++) {
        counts[e] = tot[e];         aoff[e] = p0;     p0 += (tot[e] + BM - 1) / BM * BM;
        counts[8 + e] = tot[8 + e]; aoff[9 + e] = p1; p1 += (tot[8 + e] + BM - 1) / BM * BM;
      }
      aoff[8] = p0; aoff[17] = p1;
    }
  }
  __syncthreads();
  if (blockIdx.x == 0) {
    // zero-fill pad slots so expert MODE 0 gathers a valid token index
    const int cnt_c = tot[c];
    const int padded = (cnt_c + BM - 1) / BM * BM;
    const int base = ((c >> 3) ? SLOTS : 0) + s_ao[c];
    for (int sidx = cnt_c + l; sidx < padded; sidx += 64)
      toks[base + sidx] = 0;
    // importance loss
    if (c < 8) {
      double a = 0.0;
#pragma unroll
      for (int j = 0; j < GBLK / 64; j++)
        a += (double)gpsum[(size_t)(l + j * 64) * 8 + c];
#pragma unroll
      for (int off = 32; off; off >>= 1) a += __shfl_xor(a, off, 64);
      if (l == 0) imp[c] = a;
    }
    __syncthreads();
    if (threadIdx.x == 0) {
      double mn = 0.0;
      for (int e = 0; e < 8; e++) mn += imp[e];
      mn *= (1.0 / 8.0);
      double var = 0.0;
      for (int e = 0; e < 8; e++) { double d = imp[e] - mn; var += d * d; }
      var *= (1.0 / 7.0);
      double r = sqrt(var) / mn;
      loss[0] = (float)(0.01 * r * r);
    }
  }
  // scatter this block's 256 tokens
  if (threadIdx.x < 256) {
    int n = blockIdx.x * 256 + threadIdx.x;
    int blk = n >> 4;
    int e1 = e1a[n];
    int slot = s_ao[e1] + bb[blk][e1] + r1a[n];
    toks[slot] = n; wsl[slot] = w1a[n];
    int e2 = e2a[n];
    slot = SLOTS + s_ao[8 + e2] + bb[blk][8 + e2] + r2a[n];
    toks[slot] = n; wsl[slot] = w2a[n];
  }
}

// ---------- expert GEMM: 64x128 tile, safe 2-phase dbuf ----------
// MODE 0: layer1 (x->H, relu), z = klist.
// MODE 1: layer2, z = klist; k0 -> y (f32, =), k1 -> ypart (f16, =).
template <int MODE>
__global__ __launch_bounds__(256) void k_expert(
    const f16* __restrict__ Asrc, const f16* __restrict__ Wt,
    const float* __restrict__ bias, const int* __restrict__ toks,
    const float* __restrict__ wsl, const int* __restrict__ aoff,
    const int* __restrict__ counts, f16* __restrict__ Hout,
    float* __restrict__ y, f16* __restrict__ ypart) {
  const int klist = blockIdx.z;
  const int* ao = aoff + klist * 9;
  const int slot0 = blockIdx.x * BM;
  if (slot0 >= ao[8]) return;
  int e = 0;
#pragma unroll
  for (int t = 1; t <= 7; t++) if (slot0 >= ao[t]) e = t;

  const int n0 = blockIdx.y * BN;
  const int tid = threadIdx.x, lane = tid & 63, wid = tid >> 6;

  __shared__ __align__(16) f16 As[2][BM * BK];   // 64x32
  __shared__ __align__(16) f16 Bs[2][BN * BK];   // 128x32

  const int srow = wid * 16 + (lane >> 2);       // 0..63
  const int scol = (lane & 3) * 8;

  const f16* arow;
  if (MODE == 0) {
    int tk = toks[klist * SLOTS + slot0 + srow];
    arow = Asrc + (size_t)tk * DIM + scol;
  } else {
    arow = Asrc + (size_t)(klist * SLOTS + slot0 + srow) * HIDN + scol;
  }
  const f16* brow[2];
  int bloff[2];
#pragma unroll
  for (int rnd = 0; rnd < 2; rnd++) {
    brow[rnd] = Wt + ((size_t)e * DIM + n0 + rnd * 64 + srow) * DIM + scol;
    bloff[rnd] = (rnd * 64 + wid * 16) * BK;
  }
  const int aloff = wid * 16 * BK;

  f32x4 acc[4][2] = {};
  const int fr = lane & 15, kb = (lane >> 4) * 8;

#define STAGE(buf, ks)                                    \
  {                                                       \
    gl2lds16(arow + (ks), As[buf] + aloff);               \
    _Pragma("unroll")                                     \
    for (int rnd = 0; rnd < 2; rnd++)                     \
      gl2lds16(brow[rnd] + (ks), Bs[buf] + bloff[rnd]);   \
  }

  STAGE(0, 0);
  __syncthreads();
  for (int t = 0; t < NT; t++) {
    const int cur = t & 1;
    if (t + 1 < NT) STAGE(cur ^ 1, (t + 1) * BK);   // overlap with compute below
    f16x8 af[4], bf[2];
#pragma unroll
    for (int m = 0; m < 4; m++)
      af[m] = *(const f16x8*)(As[cur] + (m * 16 + fr) * BK + kb);
#pragma unroll
    for (int n = 0; n < 2; n++)
      bf[n] = *(const f16x8*)(Bs[cur] + (wid * 32 + n * 16 + fr) * BK + kb);
#pragma unroll
    for (int m = 0; m < 4; m++)
#pragma unroll
      for (int n = 0; n < 2; n++)
        acc[m][n] = __builtin_amdgcn_mfma_f32_16x16x32_f16(af[m], bf[n], acc[m][n], 0, 0, 0);
    __syncthreads();   // drains next-tile loads + retires this tile's LDS reads
  }
#undef STAGE

  float bcol[2];
#pragma unroll
  for (int n = 0; n < 2; n++)
    bcol[n] = bias[e * ((MODE == 0) ? HIDN : DIM) + n0 + wid * 32 + n * 16 + fr];

  if (MODE == 0) {
#pragma unroll
    for (int m = 0; m < 4; m++)
#pragma unroll
      for (int r4 = 0; r4 < 4; r4++) {
        int slot = slot0 + m * 16 + (lane >> 4) * 4 + r4;
#pragma unroll
        for (int n = 0; n < 2; n++) {
          int col = n0 + wid * 32 + n * 16 + fr;
          float v = acc[m][n][r4] + bcol[n];
          Hout[(size_t)(klist * SLOTS + slot) * HIDN + col] = (f16)fmaxf(v, 0.f);
        }
      }
  } else {
    const int vend = ao[e] + counts[klist * 8 + e];
#pragma unroll
    for (int m = 0; m < 4; m++)
#pragma unroll
      for (int r4 = 0; r4 < 4; r4++) {
        int slot = slot0 + m * 16 + (lane >> 4) * 4 + r4;
        if (slot < vend) {
          int tk = toks[klist * SLOTS + slot];
          float w = wsl[klist * SLOTS + slot];
#pragma unroll
          for (int n = 0; n < 2; n++) {
            int col = n0 + wid * 32 + n * 16 + fr;
            float v = (acc[m][n][r4] + bcol[n]) * w;
            if (klist == 0) y[(size_t)tk * DIM + col] = v;
            else            ypart[(size_t)tk * DIM + col] = (f16)v;
          }
        }
      }
  }
}

// ---------- combine: y += (float)ypart ----------
__global__ __launch_bounds__(256) void k_combine(float* __restrict__ y,
                                                 const f16* __restrict__ ypart) {
  size_t i4 = ((size_t)blockIdx.x * 256 + threadIdx.x) * 4;
  float4 a = *(const float4*)(y + i4);
  f16x4 b = *(const f16x4*)(ypart + i4);
  a.x += (float)b[0]; a.y += (float)b[1]; a.z += (float)b[2]; a.w += (float)b[3];
  *(float4*)(y + i4) = a;
}

extern "C" void kernel_launch(void* const* d_in, const int* in_sizes, int n_in,
                              void* d_out, int out_size, void* d_ws, size_t ws_size,
                              hipStream_t stream) {
  const float* x  = (const float*)d_in[0];
  const float* q  = (const float*)d_in[1];
  const float* Wv = (const float*)d_in[6];
  const float* bv = (const float*)d_in[7];
  const float* Wo = (const float*)d_in[8];
  const float* bo = (const float*)d_in[9];
  const float* gW = (const float*)d_in[10];
  const float* gb = (const float*)d_in[11];
  const float* W1 = (const float*)d_in[12];
  const float* b1 = (const float*)d_in[13];
  const float* W2 = (const float*)d_in[14];
  const float* b2 = (const float*)d_in[15];

  float* out = (float*)d_out;
  float* y_out = out;
  float* gp_out = out + (size_t)NTOK * DIM;
  float* loss_out = gp_out + (size_t)NTOK * NEXP;

  uint8_t* w = (uint8_t*)d_ws;
  size_t o = 0;
  auto alloc = [&](size_t bytes) -> void* {
    void* p = w + o;
    o = (o + bytes + 255) & ~(size_t)255;
    return p;
  };
  f16* xh      = (f16*)alloc((size_t)NTOK * DIM * 2);
  f16* W1t     = (f16*)alloc((size_t)NEXP * DIM * HIDN * 2);
  f16* W2t     = (f16*)alloc((size_t)NEXP * DIM * HIDN * 2);
  f16* Hbuf    = (f16*)alloc((size_t)2 * SLOTS * HIDN * 2);
  f16* ypart   = (f16*)alloc((size_t)NTOK * DIM * 2);
  double* G1   = (double*)alloc((size_t)DIM * NEXP * 8);
  float* Wg    = (float*)alloc((size_t)DIM * NEXP * 4);
  double* bg   = (double*)alloc(NEXP * 8);
  int* e1a     = (int*)alloc(NTOK * 4);
  int* e2a     = (int*)alloc(NTOK * 4);
  float* w1a   = (float*)alloc(NTOK * 4);
  float* w2a   = (float*)alloc(NTOK * 4);
  int* r1a     = (int*)alloc(NTOK * 4);
  int* r2a     = (int*)alloc(NTOK * 4);
  int* hist    = (int*)alloc((size_t)GBLK * 16 * 4);
  float* gpsum = (float*)alloc((size_t)GBLK * 8 * 4);
  int* counts  = (int*)alloc(16 * 4);
  int* aoff    = (int*)alloc(18 * 4);
  int* toks    = (int*)alloc((size_t)2 * SLOTS * 4);
  float* wsl   = (float*)alloc((size_t)2 * SLOTS * 4);
  (void)ws_size; (void)in_sizes; (void)n_in; (void)out_size;

  k_prep<<<9216, 256, 0, stream>>>(x, xh, W1, W2, W1t, W2t, Wo, gW, G1);
  k_foldB<<<1025, 256, 0, stream>>>(Wv, G1, Wg, bv, bo, gW, gb, bg);
  k_gate<<<GBLK, 256, 0, stream>>>(q, Wg, bg, gp_out, e1a, e2a, w1a, w2a, r1a, r2a, hist, gpsum);
  k_route<<<NTOK / 256, 1024, 0, stream>>>(hist, e1a, e2a, w1a, w2a, r1a, r2a,
                                           aoff, counts, toks, wsl, gpsum, loss_out);
  k_expert<0><<<dim3(MAXRB, 4, 2), 256, 0, stream>>>(xh, W1t, b1, toks, wsl, aoff, counts,
                                                     Hbuf, nullptr, nullptr);
  k_expert<1><<<dim3(MAXRB, 4, 2), 256, 0, stream>>>(Hbuf, W2t, b2, toks, wsl, aoff, counts,
                                                     nullptr, y_out, ypart);
  k_combine<<<NTOK * DIM / 1024, 256, 0, stream>>>(y_out, ypart);
}

// Round 16
// 99.398 us; speedup vs baseline: 2.7651x; 1.0224x over previous
//
#include <hip/hip_runtime.h>
#include <math.h>
#include <stdint.h>

#define NTOK 8192
#define DIM  512
#define NEXP 8
#define HIDN 512
#define BM 64                 // row tile (tokens)
#define BN 128                // col tile
#define BK 32
#define NT  (DIM / BK)        // 16 K-steps
#define MAXRB 136             // ceil((8192 + 8*63)/64); 136 = 8*17 (divisible by NXCD)
#define SLOTS (MAXRB*BM)      // 8704
#define GBLK (NTOK/16)        // 512 gate blocks (16 tokens each)

typedef _Float16 f16;
typedef __attribute__((ext_vector_type(4))) _Float16 f16x4;
typedef __attribute__((ext_vector_type(8))) _Float16 f16x8;
typedef __attribute__((ext_vector_type(4))) float    f32x4;

__device__ __forceinline__ void gl2lds16(const void* g, void* l) {
  __builtin_amdgcn_global_load_lds(
      (const __attribute__((address_space(1))) unsigned int*)(g),
      (__attribute__((address_space(3))) unsigned int*)(l), 16, 0, 0);
}

// ---------- prep: x->f16 | W1/W2 transpose-cast | foldA (G1 = Wo @ gate_W) ----------
__global__ __launch_bounds__(256) void k_prep(
    const float* __restrict__ x, f16* __restrict__ xh,
    const float* __restrict__ W1, const float* __restrict__ W2,
    f16* __restrict__ W1t, f16* __restrict__ W2t,
    const float* __restrict__ Wo, const float* __restrict__ gW,
    double* __restrict__ G1) {
  const int bx = blockIdx.x, tid = threadIdx.x;
  if (bx < 4096) {               // x convert
    int i4 = (bx * 256 + tid) * 4;
    float4 v = *(const float4*)(x + i4);
    f16x4 o; o.x = (_Float16)v.x; o.y = (_Float16)v.y; o.z = (_Float16)v.z; o.w = (_Float16)v.w;
    *(f16x4*)(xh + i4) = o;
  } else if (bx < 8192) {        // weight transpose-cast
    __shared__ float t[32][33];
    int idx = bx - 4096;
    int z = idx >> 8, rem = idx & 255;
    int k0 = (rem >> 4) * 32, n0 = (rem & 15) * 32;
    const float* src = (z < 8 ? W1 : W2) + (size_t)(z & 7) * DIM * DIM;
    f16* dst = (z < 8 ? W1t : W2t) + (size_t)(z & 7) * DIM * DIM;
    int tx = tid & 31, ty = tid >> 5;
    for (int r = ty; r < 32; r += 8) t[r][tx] = src[(size_t)(k0 + r) * DIM + n0 + tx];
    __syncthreads();
    for (int r = ty; r < 32; r += 8) dst[(size_t)(n0 + r) * DIM + k0 + tx] = (f16)t[tx][r];
  } else {                       // foldA: G1[d][e] = sum_k Wo[d][k] * gW[k][e]  (fp64)
    int out = (bx - 8192) * 4 + (tid >> 6);
    int lane = tid & 63;
    int d = out >> 3, e = out & 7;
    double acc = 0.0;
#pragma unroll
    for (int j = 0; j < 8; j++) {
      int k = j * 64 + lane;
      acc += (double)Wo[d * DIM + k] * (double)gW[k * NEXP + e];
    }
#pragma unroll
    for (int off = 32; off; off >>= 1) acc += __shfl_xor(acc, off, 64);
    if (lane == 0) G1[out] = acc;
  }
}

// blocks 0..1023: Wg = fp32(Wv @ G1). block 1024: bg fold.
__global__ void k_foldB(const float* __restrict__ Wv, const double* __restrict__ G1,
                        float* __restrict__ Wg, const float* __restrict__ bv,
                        const float* __restrict__ bo, const float* __restrict__ gW,
                        const float* __restrict__ gb, double* __restrict__ bg) {
  int lane = threadIdx.x & 63;
  if (blockIdx.x == 1024) {
    int w = threadIdx.x >> 6;
    for (int e = w; e < NEXP; e += 4) {
      double acc = 0.0;
#pragma unroll
      for (int j = 0; j < 8; j++) {
        int d = j * 64 + lane;
        acc += (double)bv[d] * G1[d * NEXP + e] + (double)bo[d] * (double)gW[d * NEXP + e];
      }
#pragma unroll
      for (int off = 32; off; off >>= 1) acc += __shfl_xor(acc, off, 64);
      if (lane == 0) bg[e] = acc + (double)gb[e];
    }
    return;
  }
  int out = blockIdx.x * 4 + (threadIdx.x >> 6);
  int d = out >> 3, e = out & 7;
  double acc = 0.0;
#pragma unroll
  for (int j = 0; j < 8; j++) {
    int k = j * 64 + lane;
    acc += (double)Wv[d * DIM + k] * G1[k * NEXP + e];
  }
#pragma unroll
  for (int off = 32; off; off >>= 1) acc += __shfl_xor(acc, off, 64);
  if (lane == 0) Wg[out] = (float)acc;
}

// ---------- gate: thread-per-(token,expert,half). fp64 logits, fp32 softmax. ----------
__global__ __launch_bounds__(256) void k_gate(
    const float* __restrict__ q, const float* __restrict__ Wg,
    const double* __restrict__ bg, float* __restrict__ gp_out,
    int* __restrict__ e1a, int* __restrict__ e2a,
    float* __restrict__ w1a, float* __restrict__ w2a,
    int* __restrict__ r1a, int* __restrict__ r2a, int* __restrict__ hist,
    float* __restrict__ gpsum) {
  __shared__ float qs[16 * 513];
  __shared__ float ps[16][8];
  __shared__ int cnt[16];
  const int tid = threadIdx.x;
  const int tok0 = blockIdx.x * 16;

  for (int i = tid; i < 16 * 512; i += 256) {
    int r = i >> 9, c = i & 511;
    qs[r * 513 + c] = q[(size_t)(tok0 + r) * DIM + c];
  }
  if (tid < 16) cnt[tid] = 0;
  __syncthreads();

  const int e = tid & 7;
  const int half = (tid >> 3) & 1;
  const int tl = tid >> 4;
  const float* qrow = qs + tl * 513 + half * 256;
  const float* wcol = Wg + half * 256 * NEXP + e;

  double a0 = 0, a1 = 0, a2 = 0, a3 = 0;
#pragma unroll 4
  for (int j = 0; j < 256; j += 4) {
    a0 += (double)qrow[j]     * (double)wcol[(size_t)j * NEXP];
    a1 += (double)qrow[j + 1] * (double)wcol[(size_t)(j + 1) * NEXP];
    a2 += (double)qrow[j + 2] * (double)wcol[(size_t)(j + 2) * NEXP];
    a3 += (double)qrow[j + 3] * (double)wcol[(size_t)(j + 3) * NEXP];
  }
  double acc = (a0 + a1) + (a2 + a3);
  acc += __shfl_xor(acc, 8, 64);  // combine halves

  double l = acc + bg[e];
  double m = l;
#pragma unroll
  for (int off = 1; off < 8; off <<= 1) m = fmax(m, __shfl_xor(m, off, 64));
  float ex = expf((float)(l - m));
  float s = ex;
#pragma unroll
  for (int off = 1; off < 8; off <<= 1) s += __shfl_xor(s, off, 64);
  float pf = ex / s;
  int tok = tok0 + tl;
  if (half == 0) { gp_out[(size_t)tok * NEXP + e] = pf; ps[tl][e] = pf; }

  // top-1/top-2 ordered by fp64 logit (monotone == prob ordering)
  double v1 = l; int i1 = e;
#pragma unroll
  for (int off = 1; off < 8; off <<= 1) {
    double ov = __shfl_xor(v1, off, 64);
    int oi = __shfl_xor(i1, off, 64);
    if (ov > v1 || (ov == v1 && oi < i1)) { v1 = ov; i1 = oi; }
  }
  double v2 = (e == i1) ? -1e300 : l; int i2 = e;
#pragma unroll
  for (int off = 1; off < 8; off <<= 1) {
    double ov = __shfl_xor(v2, off, 64);
    int oi = __shfl_xor(i2, off, 64);
    if (ov > v2 || (ov == v2 && oi < i2)) { v2 = ov; i2 = oi; }
  }
  float p1 = __shfl(pf, (tl << 4) + i1, 64);
  float p2 = __shfl(pf, (tl << 4) + i2, 64);
  if (e == 0 && half == 0) {
    float ev = expf(p2 - p1);
    float iw = 1.0f / (1.0f + ev);
    e1a[tok] = i1; e2a[tok] = i2;
    w1a[tok] = iw; w2a[tok] = ev * iw;
    r1a[tok] = atomicAdd(&cnt[i1], 1);
    r2a[tok] = atomicAdd(&cnt[8 + i2], 1);
  }
  __syncthreads();
  if (tid < 16) hist[blockIdx.x * 16 + tid] = cnt[tid];
  if (tid < 8) {
    float ssum = 0.f;
#pragma unroll
    for (int r = 0; r < 16; r++) ssum += ps[r][tid];
    gpsum[blockIdx.x * 8 + tid] = ssum;
  }
}

// ---------- route: fused scan + scatter (+ pads, counts/aoff, imploss) ----------
__global__ __launch_bounds__(1024) void k_route(
    const int* __restrict__ hist,
    const int* __restrict__ e1a, const int* __restrict__ e2a,
    const float* __restrict__ w1a, const float* __restrict__ w2a,
    const int* __restrict__ r1a, const int* __restrict__ r2a,
    int* __restrict__ aoff, int* __restrict__ counts,
    int* __restrict__ toks, float* __restrict__ wsl,
    const float* __restrict__ gpsum, float* __restrict__ loss) {
  __shared__ int bb[GBLK][16];   // exclusive prefix per (gate-block, counter)
  __shared__ int tot[16];
  __shared__ int s_ao[16];
  __shared__ double imp[8];
  const int c = threadIdx.x >> 6;   // counter 0..15
  const int l = threadIdx.x & 63;
  int v[GBLK / 64];
  int s = 0;
#pragma unroll
  for (int j = 0; j < GBLK / 64; j++) {
    v[j] = hist[((l * (GBLK / 64) + j) << 4) + c];
    s += v[j];
  }
  int incl = s;
#pragma unroll
  for (int off = 1; off < 64; off <<= 1) {
    int t = __shfl_up(incl, off, 64);
    if (l >= off) incl += t;
  }
  int run = incl - s;  // exclusive
#pragma unroll
  for (int j = 0; j < GBLK / 64; j++) {
    bb[l * (GBLK / 64) + j][c] = run;
    run += v[j];
  }
  if (l == 63) tot[c] = incl;
  __syncthreads();
  if (threadIdx.x == 0) {
    int o0 = 0, o1 = 0;
#pragma unroll
    for (int e = 0; e < NEXP; e++) {
      s_ao[e] = o0;     o0 += (tot[e] + BM - 1) / BM * BM;
      s_ao[8 + e] = o1; o1 += (tot[8 + e] + BM - 1) / BM * BM;
    }
    if (blockIdx.x == 0) {
      int p0 = 0, p1 = 0;
#pragma unroll
      for (int e = 0; e < NEXP; e++) {
        counts[e] = tot[e];         aoff[e] = p0;     p0 += (tot[e] + BM - 1) / BM * BM;
        counts[8 + e] = tot[8 + e]; aoff[9 + e] = p1; p1 += (tot[8 + e] + BM - 1) / BM * BM;
      }
      aoff[8] = p0; aoff[17] = p1;
    }
  }
  __syncthreads();
  if (blockIdx.x == 0) {
    // zero-fill pad slots so expert MODE 0 gathers a valid token index
    const int cnt_c = tot[c];
    const int padded = (cnt_c + BM - 1) / BM * BM;
    const int base = ((c >> 3) ? SLOTS : 0) + s_ao[c];
    for (int sidx = cnt_c + l; sidx < padded; sidx += 64)
      toks[base + sidx] = 0;
    // importance loss
    if (c < 8) {
      double a = 0.0;
#pragma unroll
      for (int j = 0; j < GBLK / 64; j++)
        a += (double)gpsum[(size_t)(l + j * 64) * 8 + c];
#pragma unroll
      for (int off = 32; off; off >>= 1) a += __shfl_xor(a, off, 64);
      if (l == 0) imp[c] = a;
    }
    __syncthreads();
    if (threadIdx.x == 0) {
      double mn = 0.0;
      for (int e = 0; e < 8; e++) mn += imp[e];
      mn *= (1.0 / 8.0);
      double var = 0.0;
      for (int e = 0; e < 8; e++) { double d = imp[e] - mn; var += d * d; }
      var *= (1.0 / 7.0);
      double r = sqrt(var) / mn;
      loss[0] = (float)(0.01 * r * r);
    }
  }
  // scatter this block's 256 tokens
  if (threadIdx.x < 256) {
    int n = blockIdx.x * 256 + threadIdx.x;
    int blk = n >> 4;
    int e1 = e1a[n];
    int slot = s_ao[e1] + bb[blk][e1] + r1a[n];
    toks[slot] = n; wsl[slot] = w1a[n];
    int e2 = e2a[n];
    slot = SLOTS + s_ao[8 + e2] + bb[blk][8 + e2] + r2a[n];
    toks[slot] = n; wsl[slot] = w2a[n];
  }
}

// ---------- expert GEMM: 64x128 tile, safe 2-phase dbuf, XCD-swizzled x ----------
// blockIdx.x remap: swz = (b&7)*17 + (b>>3)  (bijective since MAXRB=136=8*17).
// Consecutive slot-ranges (same expert's B-panel) land on the same XCD -> L2 hits.
// MODE 0: layer1 (x->H, relu), z = klist.
// MODE 1: layer2, z = klist; k0 -> y (f32, =), k1 -> ypart (f16, =).
template <int MODE>
__global__ __launch_bounds__(256) void k_expert(
    const f16* __restrict__ Asrc, const f16* __restrict__ Wt,
    const float* __restrict__ bias, const int* __restrict__ toks,
    const float* __restrict__ wsl, const int* __restrict__ aoff,
    const int* __restrict__ counts, f16* __restrict__ Hout,
    float* __restrict__ y, f16* __restrict__ ypart) {
  const int klist = blockIdx.z;
  const int* ao = aoff + klist * 9;
  const int bswz = (blockIdx.x & 7) * (MAXRB / 8) + (blockIdx.x >> 3);
  const int slot0 = bswz * BM;
  if (slot0 >= ao[8]) return;
  int e = 0;
#pragma unroll
  for (int t = 1; t <= 7; t++) if (slot0 >= ao[t]) e = t;

  const int n0 = blockIdx.y * BN;
  const int tid = threadIdx.x, lane = tid & 63, wid = tid >> 6;

  __shared__ __align__(16) f16 As[2][BM * BK];   // 64x32
  __shared__ __align__(16) f16 Bs[2][BN * BK];   // 128x32

  const int srow = wid * 16 + (lane >> 2);       // 0..63
  const int scol = (lane & 3) * 8;

  const f16* arow;
  if (MODE == 0) {
    int tk = toks[klist * SLOTS + slot0 + srow];
    arow = Asrc + (size_t)tk * DIM + scol;
  } else {
    arow = Asrc + (size_t)(klist * SLOTS + slot0 + srow) * HIDN + scol;
  }
  const f16* brow[2];
  int bloff[2];
#pragma unroll
  for (int rnd = 0; rnd < 2; rnd++) {
    brow[rnd] = Wt + ((size_t)e * DIM + n0 + rnd * 64 + srow) * DIM + scol;
    bloff[rnd] = (rnd * 64 + wid * 16) * BK;
  }
  const int aloff = wid * 16 * BK;

  f32x4 acc[4][2] = {};
  const int fr = lane & 15, kb = (lane >> 4) * 8;

#define STAGE(buf, ks)                                    \
  {                                                       \
    gl2lds16(arow + (ks), As[buf] + aloff);               \
    _Pragma("unroll")                                     \
    for (int rnd = 0; rnd < 2; rnd++)                     \
      gl2lds16(brow[rnd] + (ks), Bs[buf] + bloff[rnd]);   \
  }

  STAGE(0, 0);
  __syncthreads();
  for (int t = 0; t < NT; t++) {
    const int cur = t & 1;
    if (t + 1 < NT) STAGE(cur ^ 1, (t + 1) * BK);   // overlap with compute below
    f16x8 af[4], bf[2];
#pragma unroll
    for (int m = 0; m < 4; m++)
      af[m] = *(const f16x8*)(As[cur] + (m * 16 + fr) * BK + kb);
#pragma unroll
    for (int n = 0; n < 2; n++)
      bf[n] = *(const f16x8*)(Bs[cur] + (wid * 32 + n * 16 + fr) * BK + kb);
#pragma unroll
    for (int m = 0; m < 4; m++)
#pragma unroll
      for (int n = 0; n < 2; n++)
        acc[m][n] = __builtin_amdgcn_mfma_f32_16x16x32_f16(af[m], bf[n], acc[m][n], 0, 0, 0);
    __syncthreads();   // drains next-tile loads + retires this tile's LDS reads
  }
#undef STAGE

  float bcol[2];
#pragma unroll
  for (int n = 0; n < 2; n++)
    bcol[n] = bias[e * ((MODE == 0) ? HIDN : DIM) + n0 + wid * 32 + n * 16 + fr];

  if (MODE == 0) {
#pragma unroll
    for (int m = 0; m < 4; m++)
#pragma unroll
      for (int r4 = 0; r4 < 4; r4++) {
        int slot = slot0 + m * 16 + (lane >> 4) * 4 + r4;
#pragma unroll
        for (int n = 0; n < 2; n++) {
          int col = n0 + wid * 32 + n * 16 + fr;
          float v = acc[m][n][r4] + bcol[n];
          Hout[(size_t)(klist * SLOTS + slot) * HIDN + col] = (f16)fmaxf(v, 0.f);
        }
      }
  } else {
    const int vend = ao[e] + counts[klist * 8 + e];
#pragma unroll
    for (int m = 0; m < 4; m++)
#pragma unroll
      for (int r4 = 0; r4 < 4; r4++) {
        int slot = slot0 + m * 16 + (lane >> 4) * 4 + r4;
        if (slot < vend) {
          int tk = toks[klist * SLOTS + slot];
          float w = wsl[klist * SLOTS + slot];
#pragma unroll
          for (int n = 0; n < 2; n++) {
            int col = n0 + wid * 32 + n * 16 + fr;
            float v = (acc[m][n][r4] + bcol[n]) * w;
            if (klist == 0) y[(size_t)tk * DIM + col] = v;
            else            ypart[(size_t)tk * DIM + col] = (f16)v;
          }
        }
      }
  }
}

// ---------- combine: y += (float)ypart ----------
__global__ __launch_bounds__(256) void k_combine(float* __restrict__ y,
                                                 const f16* __restrict__ ypart) {
  size_t i4 = ((size_t)blockIdx.x * 256 + threadIdx.x) * 4;
  float4 a = *(const float4*)(y + i4);
  f16x4 b = *(const f16x4*)(ypart + i4);
  a.x += (float)b[0]; a.y += (float)b[1]; a.z += (float)b[2]; a.w += (float)b[3];
  *(float4*)(y + i4) = a;
}

extern "C" void kernel_launch(void* const* d_in, const int* in_sizes, int n_in,
                              void* d_out, int out_size, void* d_ws, size_t ws_size,
                              hipStream_t stream) {
  const float* x  = (const float*)d_in[0];
  const float* q  = (const float*)d_in[1];
  const float* Wv = (const float*)d_in[6];
  const float* bv = (const float*)d_in[7];
  const float* Wo = (const float*)d_in[8];
  const float* bo = (const float*)d_in[9];
  const float* gW = (const float*)d_in[10];
  const float* gb = (const float*)d_in[11];
  const float* W1 = (const float*)d_in[12];
  const float* b1 = (const float*)d_in[13];
  const float* W2 = (const float*)d_in[14];
  const float* b2 = (const float*)d_in[15];

  float* out = (float*)d_out;
  float* y_out = out;
  float* gp_out = out + (size_t)NTOK * DIM;
  float* loss_out = gp_out + (size_t)NTOK * NEXP;

  uint8_t* w = (uint8_t*)d_ws;
  size_t o = 0;
  auto alloc = [&](size_t bytes) -> void* {
    void* p = w + o;
    o = (o + bytes + 255) & ~(size_t)255;
    return p;
  };
  f16* xh      = (f16*)alloc((size_t)NTOK * DIM * 2);
  f16* W1t     = (f16*)alloc((size_t)NEXP * DIM * HIDN * 2);
  f16* W2t     = (f16*)alloc((size_t)NEXP * DIM * HIDN * 2);
  f16* Hbuf    = (f16*)alloc((size_t)2 * SLOTS * HIDN * 2);
  f16* ypart   = (f16*)alloc((size_t)NTOK * DIM * 2);
  double* G1   = (double*)alloc((size_t)DIM * NEXP * 8);
  float* Wg    = (float*)alloc((size_t)DIM * NEXP * 4);
  double* bg   = (double*)alloc(NEXP * 8);
  int* e1a     = (int*)alloc(NTOK * 4);
  int* e2a     = (int*)alloc(NTOK * 4);
  float* w1a   = (float*)alloc(NTOK * 4);
  float* w2a   = (float*)alloc(NTOK * 4);
  int* r1a     = (int*)alloc(NTOK * 4);
  int* r2a     = (int*)alloc(NTOK * 4);
  int* hist    = (int*)alloc((size_t)GBLK * 16 * 4);
  float* gpsum = (float*)alloc((size_t)GBLK * 8 * 4);
  int* counts  = (int*)alloc(16 * 4);
  int* aoff    = (int*)alloc(18 * 4);
  int* toks    = (int*)alloc((size_t)2 * SLOTS * 4);
  float* wsl   = (float*)alloc((size_t)2 * SLOTS * 4);
  (void)ws_size; (void)in_sizes; (void)n_in; (void)out_size;

  k_prep<<<9216, 256, 0, stream>>>(x, xh, W1, W2, W1t, W2t, Wo, gW, G1);
  k_foldB<<<1025, 256, 0, stream>>>(Wv, G1, Wg, bv, bo, gW, gb, bg);
  k_gate<<<GBLK, 256, 0, stream>>>(q, Wg, bg, gp_out, e1a, e2a, w1a, w2a, r1a, r2a, hist, gpsum);
  k_route<<<NTOK / 256, 1024, 0, stream>>>(hist, e1a, e2a, w1a, w2a, r1a, r2a,
                                           aoff, counts, toks, wsl, gpsum, loss_out);
  k_expert<0><<<dim3(MAXRB, 4, 2), 256, 0, stream>>>(xh, W1t, b1, toks, wsl, aoff, counts,
                                                     Hbuf, nullptr, nullptr);
  k_expert<1><<<dim3(MAXRB, 4, 2), 256, 0, stream>>>(Hbuf, W2t, b2, toks, wsl, aoff, counts,
                                                     nullptr, y_out, ypart);
  k_combine<<<NTOK * DIM / 1024, 256, 0, stream>>>(y_out, ypart);
}